// Round 1
// baseline (295.001 us; speedup 1.0000x reference)
//
#include <hip/hip_runtime.h>

#define NP   8732   // priors
#define NB   32     // batch
#define NOBJ 16     // truths per image
#define NC   81     // classes

__device__ __forceinline__ float sl1(float x) {
  float d = fabsf(x);
  return d < 1.0f ? 0.5f * d * d : d - 0.5f;
}

// ---------------- Kernel A: matching + localization loss ----------------
__global__ __launch_bounds__(256) void kmatch(
    const float* __restrict__ loc, const float* __restrict__ targets,
    const float* __restrict__ priors, int* __restrict__ conf_t,
    int* __restrict__ num_pos, float* __restrict__ facc, int* __restrict__ iacc)
{
  const int b = blockIdx.x;
  const int tid = threadIdx.x;
  __shared__ float tx0[NOBJ], ty0[NOBJ], tx1[NOBJ], ty1[NOBJ], tarea[NOBJ];
  __shared__ int tlab[NOBJ];
  __shared__ unsigned long long bestPr[NOBJ];
  __shared__ float bto_s[NP];
  __shared__ short bti_s[NP];
  __shared__ float redf[4];
  __shared__ int   redi[4];

  if (tid < NOBJ) {
    const float* tg = targets + (b * NOBJ + tid) * 5;
    float x0 = tg[0], y0 = tg[1], x1 = tg[2], y1 = tg[3];
    tx0[tid] = x0; ty0[tid] = y0; tx1[tid] = x1; ty1[tid] = y1;
    tarea[tid] = (x1 - x0) * (y1 - y0);
    tlab[tid] = (int)tg[4];
    bestPr[tid] = 0ull;
  }
  __syncthreads();

  // thread-local per-truth argmax over this thread's priors (static-indexed, unrolled)
  float bv[NOBJ];
  int   bp[NOBJ];
  #pragma unroll
  for (int n = 0; n < NOBJ; ++n) { bv[n] = -1.0f; bp[n] = 0; }

  for (int p = tid; p < NP; p += 256) {
    float4 pr = reinterpret_cast<const float4*>(priors)[p];
    float px0 = pr.x - pr.z * 0.5f;
    float py0 = pr.y - pr.w * 0.5f;
    float px1 = pr.x + pr.z * 0.5f;
    float py1 = pr.y + pr.w * 0.5f;
    float parea = (px1 - px0) * (py1 - py0);
    float bestov = -1.0f; int bestn = 0;
    #pragma unroll
    for (int n = 0; n < NOBJ; ++n) {
      float w = fminf(tx1[n], px1) - fmaxf(tx0[n], px0);
      float h = fminf(ty1[n], py1) - fmaxf(ty0[n], py0);
      w = fmaxf(w, 0.0f); h = fmaxf(h, 0.0f);
      float inter = w * h;
      float iou = inter / (tarea[n] + parea - inter);
      if (iou > bv[n]) { bv[n] = iou; bp[n] = p; }     // first-occurrence: strict >
      if (iou > bestov) { bestov = iou; bestn = n; }   // first-occurrence over n
    }
    bto_s[p] = bestov;
    bti_s[p] = (short)bestn;
  }
  // cross-thread argmax: pack (iou_bits, NP - p) so equal iou -> smaller p wins
  #pragma unroll
  for (int n = 0; n < NOBJ; ++n) {
    unsigned long long key =
        ((unsigned long long)__float_as_uint(bv[n]) << 32) | (unsigned)(NP - bp[n]);
    atomicMax(&bestPr[n], key);
  }
  __syncthreads();
  if (tid == 0) {
    // forced matches, sequential (last truth wins on duplicate prior)
    for (int n = 0; n < NOBJ; ++n) {
      int p = NP - (int)(bestPr[n] & 0xFFFFFFFFull);
      bto_s[p] = 2.0f;
      bti_s[p] = (short)n;
    }
  }
  __syncthreads();

  float lsum = 0.0f; int pcnt = 0;
  for (int p = tid; p < NP; p += 256) {
    float ov = bto_s[p];
    int n = bti_s[p];
    int c = (ov < 0.5f) ? 0 : (tlab[n] + 1);
    conf_t[b * NP + p] = c;
    if (c > 0) {
      ++pcnt;
      float4 pr = reinterpret_cast<const float4*>(priors)[p];
      float mx0 = tx0[n], my0 = ty0[n], mx1 = tx1[n], my1 = ty1[n];
      float gx = ((mx0 + mx1) * 0.5f - pr.x) / (0.1f * pr.z);
      float gy = ((my0 + my1) * 0.5f - pr.y) / (0.1f * pr.w);
      float gw = logf((mx1 - mx0) / pr.z) / 0.2f;
      float gh = logf((my1 - my0) / pr.w) / 0.2f;
      float4 ld = reinterpret_cast<const float4*>(loc)[b * NP + p];
      lsum += sl1(ld.x - gx) + sl1(ld.y - gy) + sl1(ld.z - gw) + sl1(ld.w - gh);
    }
  }
  #pragma unroll
  for (int s = 32; s >= 1; s >>= 1) {
    lsum += __shfl_xor(lsum, s, 64);
    pcnt += __shfl_xor(pcnt, s, 64);
  }
  if ((tid & 63) == 0) { redf[tid >> 6] = lsum; redi[tid >> 6] = pcnt; }
  __syncthreads();
  if (tid == 0) {
    float lt = redf[0] + redf[1] + redf[2] + redf[3];
    int   pt = redi[0] + redi[1] + redi[2] + redi[3];
    num_pos[b] = pt;
    atomicAdd(&facc[0], lt);
    atomicAdd(&iacc[0], pt);
  }
}

// ---------------- Kernel B: per-prior cross entropy (HBM-bound) ----------------
__global__ __launch_bounds__(256) void kce(
    const float* __restrict__ conf, const int* __restrict__ conf_t,
    float* __restrict__ mine, float* __restrict__ facc)
{
  const int lane = threadIdx.x & 15;           // 16 lanes per row
  const int gid  = blockIdx.x * (blockDim.x >> 4) + (threadIdx.x >> 4);
  const int stride = gridDim.x * (blockDim.x >> 4);
  const int totalRows = NB * NP;
  float cepos = 0.0f;
  for (int r = gid; r < totalRows; r += stride) {
    const float* row = conf + (size_t)r * NC;
    float x0 = row[lane];
    float x1 = row[lane + 16];
    float x2 = row[lane + 32];
    float x3 = row[lane + 48];
    float x4 = row[lane + 64];
    float x5 = (lane == 0) ? row[80] : -3.0e38f;
    float m = fmaxf(fmaxf(fmaxf(x0, x1), fmaxf(x2, x3)), fmaxf(x4, x5));
    #pragma unroll
    for (int s = 8; s >= 1; s >>= 1) m = fmaxf(m, __shfl_xor(m, s, 16));
    float sum = expf(x0 - m) + expf(x1 - m) + expf(x2 - m) +
                expf(x3 - m) + expf(x4 - m);
    if (lane == 0) sum += expf(x5 - m);
    #pragma unroll
    for (int s = 8; s >= 1; s >>= 1) sum += __shfl_xor(sum, s, 16);
    if (lane == 0) {
      float lse = m + logf(sum);
      int ct = conf_t[r];
      float ce = lse - row[ct];
      bool pos = ct > 0;
      mine[r] = pos ? 0.0f : ce;
      if (pos) cepos += ce;
    }
  }
  __shared__ float redf[4];
  #pragma unroll
  for (int s = 32; s >= 1; s >>= 1) cepos += __shfl_xor(cepos, s, 64);
  if ((threadIdx.x & 63) == 0) redf[threadIdx.x >> 6] = cepos;
  __syncthreads();
  if (threadIdx.x == 0)
    atomicAdd(&facc[1], redf[0] + redf[1] + redf[2] + redf[3]);
}

// ---------------- Kernel C: exact top-k sum per batch ----------------
__global__ __launch_bounds__(256) void ktopk(
    const float* __restrict__ mine, const int* __restrict__ num_pos,
    float* __restrict__ facc)
{
  const int b = blockIdx.x;
  const int tid = threadIdx.x;
  __shared__ float v[NP];
  __shared__ int   redi[4];
  __shared__ float redf[4];
  const float* src = mine + (size_t)b * NP;
  for (int i = tid; i < NP; i += 256) v[i] = src[i];
  __syncthreads();
  int k = 3 * num_pos[b];
  if (k > NP - 1) k = NP - 1;
  if (k <= 0) return;
  // find k-th largest value exactly: min u with count(v > f(u)) < k  (v >= 0)
  unsigned lo = 0u, hi = 0x7f800000u;
  while (lo < hi) {
    unsigned mid = lo + ((hi - lo) >> 1);
    float thr = __uint_as_float(mid);
    int c = 0;
    for (int i = tid; i < NP; i += 256) c += (v[i] > thr) ? 1 : 0;
    #pragma unroll
    for (int s = 32; s >= 1; s >>= 1) c += __shfl_xor(c, s, 64);
    if ((tid & 63) == 0) redi[tid >> 6] = c;
    __syncthreads();
    int total = redi[0] + redi[1] + redi[2] + redi[3];
    if (total < k) hi = mid; else lo = mid + 1;
    __syncthreads();
  }
  float vk = __uint_as_float(lo);
  int cgt = 0; float s = 0.0f;
  for (int i = tid; i < NP; i += 256) {
    float val = v[i];
    if (val > vk) { ++cgt; s += val; }
  }
  #pragma unroll
  for (int sh = 32; sh >= 1; sh >>= 1) {
    cgt += __shfl_xor(cgt, sh, 64);
    s   += __shfl_xor(s,   sh, 64);
  }
  if ((tid & 63) == 0) { redi[tid >> 6] = cgt; redf[tid >> 6] = s; }
  __syncthreads();
  if (tid == 0) {
    int   c   = redi[0] + redi[1] + redi[2] + redi[3];
    float tot = redf[0] + redf[1] + redf[2] + redf[3] + (float)(k - c) * vk;
    atomicAdd(&facc[2], tot);
  }
}

// ---------------- Kernel D: final normalization ----------------
__global__ void kfinal(const float* __restrict__ facc,
                       const int* __restrict__ iacc, float* __restrict__ out)
{
  float N = (float)iacc[0];
  out[0] = facc[0] / N;                 // LOC_WEIGHT = 1.0
  out[1] = (facc[1] + facc[2]) / N;
}

extern "C" void kernel_launch(void* const* d_in, const int* in_sizes, int n_in,
                              void* d_out, int out_size, void* d_ws, size_t ws_size,
                              hipStream_t stream) {
  const float* loc     = (const float*)d_in[0];
  const float* conf    = (const float*)d_in[1];
  const float* targets = (const float*)d_in[2];
  const float* priors  = (const float*)d_in[3];
  float* out = (float*)d_out;

  // workspace layout
  float* facc    = (float*)d_ws;                 // [0] loss_l  [1] ce_pos  [2] topk
  int*   iacc    = (int*)d_ws + 4;               // [0] total positives
  int*   num_pos = (int*)d_ws + 8;               // [NB]
  int*   conf_t  = (int*)d_ws + 64;              // NB*NP ints
  float* mine    = (float*)d_ws + 64 + NB * NP;  // NB*NP floats

  hipMemsetAsync(d_ws, 0, 256, stream);
  hipLaunchKernelGGL(kmatch, dim3(NB), dim3(256), 0, stream,
                     loc, targets, priors, conf_t, num_pos, facc, iacc);
  hipLaunchKernelGGL(kce, dim3(2048), dim3(256), 0, stream,
                     conf, conf_t, mine, facc);
  hipLaunchKernelGGL(ktopk, dim3(NB), dim3(256), 0, stream,
                     mine, num_pos, facc);
  hipLaunchKernelGGL(kfinal, dim3(1), dim3(1), 0, stream, facc, iacc, out);
}

// Round 2
// 227.961 us; speedup vs baseline: 1.2941x; 1.2941x over previous
//
#include <hip/hip_runtime.h>

#define NP     8732   // priors
#define NB     32     // batch
#define NOBJ   16     // truths per image
#define NC     81     // classes
#define CHUNKS 16
#define CHUNK  ((NP + CHUNKS - 1) / CHUNKS)   // 546

__device__ __forceinline__ float sl1(float x) {
  float d = fabsf(x);
  return d < 1.0f ? 0.5f * d * d : d - 0.5f;
}

// ------------- Kernel A1: per-truth best prior (argmax over priors) -------------
__global__ __launch_bounds__(256) void kbestprior(
    const float* __restrict__ targets, const float* __restrict__ priors,
    unsigned long long* __restrict__ bestPr)
{
  const int b   = blockIdx.y;
  const int p0  = blockIdx.x * CHUNK;
  const int p1  = min(NP, p0 + CHUNK);
  const int tid = threadIdx.x;
  __shared__ float tx0[NOBJ], ty0[NOBJ], tx1[NOBJ], ty1[NOBJ], tarea[NOBJ];
  __shared__ unsigned long long sbest[NOBJ];

  if (tid < NOBJ) {
    const float* tg = targets + (b * NOBJ + tid) * 5;
    float x0 = tg[0], y0 = tg[1], x1 = tg[2], y1 = tg[3];
    tx0[tid] = x0; ty0[tid] = y0; tx1[tid] = x1; ty1[tid] = y1;
    tarea[tid] = (x1 - x0) * (y1 - y0);
    sbest[tid] = 0ull;
  }
  __syncthreads();

  float bv[NOBJ]; int bp[NOBJ];
  #pragma unroll
  for (int n = 0; n < NOBJ; ++n) { bv[n] = -1.0f; bp[n] = 0; }

  for (int p = p0 + tid; p < p1; p += 256) {
    float4 pr = reinterpret_cast<const float4*>(priors)[p];
    float px0 = pr.x - pr.z * 0.5f;
    float py0 = pr.y - pr.w * 0.5f;
    float px1 = pr.x + pr.z * 0.5f;
    float py1 = pr.y + pr.w * 0.5f;
    float parea = (px1 - px0) * (py1 - py0);
    #pragma unroll
    for (int n = 0; n < NOBJ; ++n) {
      float w = fminf(tx1[n], px1) - fmaxf(tx0[n], px0);
      float h = fminf(ty1[n], py1) - fmaxf(ty0[n], py0);
      w = fmaxf(w, 0.0f); h = fmaxf(h, 0.0f);
      float inter = w * h;
      float iou = inter / (tarea[n] + parea - inter);
      if (iou > bv[n]) { bv[n] = iou; bp[n] = p; }   // first occurrence: strict >
    }
  }
  // pack (iou_bits, NP - p): equal iou -> smaller p wins (first occurrence)
  #pragma unroll
  for (int n = 0; n < NOBJ; ++n) {
    unsigned long long key = (bv[n] < 0.0f) ? 0ull :
        (((unsigned long long)__float_as_uint(bv[n]) << 32) | (unsigned)(NP - bp[n]));
    #pragma unroll
    for (int s = 1; s < 64; s <<= 1) {
      unsigned long long o = __shfl_xor(key, s, 64);
      key = (o > key) ? o : key;
    }
    if ((tid & 63) == 0) atomicMax(&sbest[n], key);
  }
  __syncthreads();
  if (tid < NOBJ) atomicMax(&bestPr[b * NOBJ + tid], sbest[tid]);
}

// ------------- Kernel A2: assignment + localization loss -------------
__global__ __launch_bounds__(256) void kassign(
    const float* __restrict__ loc, const float* __restrict__ targets,
    const float* __restrict__ priors, const unsigned long long* __restrict__ bestPr,
    int* __restrict__ conf_t, int* __restrict__ num_pos,
    float* __restrict__ facc, int* __restrict__ iacc)
{
  const int b   = blockIdx.y;
  const int p0  = blockIdx.x * CHUNK;
  const int p1  = min(NP, p0 + CHUNK);
  const int tid = threadIdx.x;
  __shared__ float tx0[NOBJ], ty0[NOBJ], tx1[NOBJ], ty1[NOBJ], tarea[NOBJ];
  __shared__ int tlab[NOBJ], decP[NOBJ];
  __shared__ float redf[4];
  __shared__ int   redi[4];

  if (tid < NOBJ) {
    const float* tg = targets + (b * NOBJ + tid) * 5;
    float x0 = tg[0], y0 = tg[1], x1 = tg[2], y1 = tg[3];
    tx0[tid] = x0; ty0[tid] = y0; tx1[tid] = x1; ty1[tid] = y1;
    tarea[tid] = (x1 - x0) * (y1 - y0);
    tlab[tid] = (int)tg[4];
    decP[tid] = NP - (int)(bestPr[b * NOBJ + tid] & 0xFFFFFFFFull);
  }
  __syncthreads();

  float lsum = 0.0f; int pcnt = 0;
  for (int p = p0 + tid; p < p1; p += 256) {
    float4 pr = reinterpret_cast<const float4*>(priors)[p];
    float px0 = pr.x - pr.z * 0.5f;
    float py0 = pr.y - pr.w * 0.5f;
    float px1 = pr.x + pr.z * 0.5f;
    float py1 = pr.y + pr.w * 0.5f;
    float parea = (px1 - px0) * (py1 - py0);
    float bestov = -1.0f; int bestn = 0;
    #pragma unroll
    for (int n = 0; n < NOBJ; ++n) {
      float w = fminf(tx1[n], px1) - fmaxf(tx0[n], px0);
      float h = fminf(ty1[n], py1) - fmaxf(ty0[n], py0);
      w = fmaxf(w, 0.0f); h = fmaxf(h, 0.0f);
      float inter = w * h;
      float iou = inter / (tarea[n] + parea - inter);
      if (iou > bestov) { bestov = iou; bestn = n; }  // first occurrence over n
    }
    // forced-match override: sequential last-wins -> take the LARGEST n matching p
    #pragma unroll
    for (int n = 0; n < NOBJ; ++n)
      if (decP[n] == p) { bestn = n; bestov = 2.0f; }
    int c = (bestov < 0.5f) ? 0 : (tlab[bestn] + 1);
    conf_t[b * NP + p] = c;
    if (c > 0) {
      ++pcnt;
      int n = bestn;
      float mx0 = tx0[n], my0 = ty0[n], mx1 = tx1[n], my1 = ty1[n];
      float gx = ((mx0 + mx1) * 0.5f - pr.x) / (0.1f * pr.z);
      float gy = ((my0 + my1) * 0.5f - pr.y) / (0.1f * pr.w);
      float gw = logf((mx1 - mx0) / pr.z) / 0.2f;
      float gh = logf((my1 - my0) / pr.w) / 0.2f;
      float4 ld = reinterpret_cast<const float4*>(loc)[b * NP + p];
      lsum += sl1(ld.x - gx) + sl1(ld.y - gy) + sl1(ld.z - gw) + sl1(ld.w - gh);
    }
  }
  #pragma unroll
  for (int s = 32; s >= 1; s >>= 1) {
    lsum += __shfl_xor(lsum, s, 64);
    pcnt += __shfl_xor(pcnt, s, 64);
  }
  if ((tid & 63) == 0) { redf[tid >> 6] = lsum; redi[tid >> 6] = pcnt; }
  __syncthreads();
  if (tid == 0) {
    float lt = redf[0] + redf[1] + redf[2] + redf[3];
    int   pt = redi[0] + redi[1] + redi[2] + redi[3];
    atomicAdd(&num_pos[b], pt);
    atomicAdd(&facc[0], lt);
    atomicAdd(&iacc[0], pt);
  }
}

// ------------- Kernel B: per-prior cross entropy (HBM-bound) -------------
__global__ __launch_bounds__(256) void kce(
    const float* __restrict__ conf, const int* __restrict__ conf_t,
    float* __restrict__ mine, float* __restrict__ facc)
{
  const int lane = threadIdx.x & 15;           // 16 lanes per row
  const int gid  = blockIdx.x * (blockDim.x >> 4) + (threadIdx.x >> 4);
  const int stride = gridDim.x * (blockDim.x >> 4);
  const int totalRows = NB * NP;
  float cepos = 0.0f;
  for (int r = gid; r < totalRows; r += stride) {
    const float* row = conf + (size_t)r * NC;
    float x0 = row[lane];
    float x1 = row[lane + 16];
    float x2 = row[lane + 32];
    float x3 = row[lane + 48];
    float x4 = row[lane + 64];
    float x5 = (lane == 0) ? row[80] : -3.0e38f;
    float m = fmaxf(fmaxf(fmaxf(x0, x1), fmaxf(x2, x3)), fmaxf(x4, x5));
    #pragma unroll
    for (int s = 8; s >= 1; s >>= 1) m = fmaxf(m, __shfl_xor(m, s, 16));
    float sum = expf(x0 - m) + expf(x1 - m) + expf(x2 - m) +
                expf(x3 - m) + expf(x4 - m);
    if (lane == 0) sum += expf(x5 - m);
    #pragma unroll
    for (int s = 8; s >= 1; s >>= 1) sum += __shfl_xor(sum, s, 16);
    if (lane == 0) {
      float lse = m + logf(sum);
      int ct = conf_t[r];
      float ce = lse - row[ct];
      bool pos = ct > 0;
      mine[r] = pos ? 0.0f : ce;
      if (pos) cepos += ce;
    }
  }
  __shared__ float redf[4];
  #pragma unroll
  for (int s = 32; s >= 1; s >>= 1) cepos += __shfl_xor(cepos, s, 64);
  if ((threadIdx.x & 63) == 0) redf[threadIdx.x >> 6] = cepos;
  __syncthreads();
  if (threadIdx.x == 0)
    atomicAdd(&facc[1], redf[0] + redf[1] + redf[2] + redf[3]);
}

// ------------- Kernel C: exact top-k sum per batch -------------
__global__ __launch_bounds__(1024) void ktopk(
    const float* __restrict__ mine, const int* __restrict__ num_pos,
    float* __restrict__ facc)
{
  const int b = blockIdx.x;
  const int tid = threadIdx.x;
  const int wid = tid >> 6;
  __shared__ float v[NP];
  __shared__ int   redi[16];
  __shared__ float redf[16];
  __shared__ int   bcast;
  const float* src = mine + (size_t)b * NP;
  for (int i = tid; i < NP; i += 1024) v[i] = src[i];
  __syncthreads();
  int k = 3 * num_pos[b];
  if (k > NP - 1) k = NP - 1;
  if (k <= 0) return;
  // exact k-th largest: min u with count(v > f(u)) < k    (v >= 0)
  unsigned lo = 0u, hi = 0x7f800000u;
  while (lo < hi) {
    unsigned mid = lo + ((hi - lo) >> 1);
    float thr = __uint_as_float(mid);
    int c = 0;
    for (int i = tid; i < NP; i += 1024) c += (v[i] > thr) ? 1 : 0;
    #pragma unroll
    for (int s = 32; s >= 1; s >>= 1) c += __shfl_xor(c, s, 64);
    if ((tid & 63) == 0) redi[wid] = c;
    __syncthreads();
    if (tid == 0) {
      int t = 0;
      #pragma unroll
      for (int w = 0; w < 16; ++w) t += redi[w];
      bcast = t;
    }
    __syncthreads();
    if (bcast < k) hi = mid; else lo = mid + 1;
  }
  float vk = __uint_as_float(lo);
  int cgt = 0; float s = 0.0f;
  for (int i = tid; i < NP; i += 1024) {
    float val = v[i];
    if (val > vk) { ++cgt; s += val; }
  }
  #pragma unroll
  for (int sh = 32; sh >= 1; sh >>= 1) {
    cgt += __shfl_xor(cgt, sh, 64);
    s   += __shfl_xor(s,   sh, 64);
  }
  if ((tid & 63) == 0) { redi[wid] = cgt; redf[wid] = s; }
  __syncthreads();
  if (tid == 0) {
    int c = 0; float tot = 0.0f;
    #pragma unroll
    for (int w = 0; w < 16; ++w) { c += redi[w]; tot += redf[w]; }
    tot += (float)(k - c) * vk;
    atomicAdd(&facc[2], tot);
  }
}

// ------------- Kernel D: final normalization -------------
__global__ void kfinal(const float* __restrict__ facc,
                       const int* __restrict__ iacc, float* __restrict__ out)
{
  float N = (float)iacc[0];
  out[0] = facc[0] / N;                 // LOC_WEIGHT = 1.0
  out[1] = (facc[1] + facc[2]) / N;
}

extern "C" void kernel_launch(void* const* d_in, const int* in_sizes, int n_in,
                              void* d_out, int out_size, void* d_ws, size_t ws_size,
                              hipStream_t stream) {
  const float* loc     = (const float*)d_in[0];
  const float* conf    = (const float*)d_in[1];
  const float* targets = (const float*)d_in[2];
  const float* priors  = (const float*)d_in[3];
  float* out = (float*)d_out;

  // workspace layout
  float* facc    = (float*)d_ws;                        // [0] loss_l [1] ce_pos [2] topk
  int*   iacc    = (int*)d_ws + 4;                      // [0] total positives
  int*   num_pos = (int*)d_ws + 8;                      // [NB]
  unsigned long long* bestPr =
      (unsigned long long*)((char*)d_ws + 256);         // NB*NOBJ u64
  int*   conf_t  = (int*)((char*)d_ws + 8192);          // NB*NP ints
  float* mine    = (float*)((char*)d_ws + 8192) + NB * NP;

  hipMemsetAsync(d_ws, 0, 4608, stream);
  hipLaunchKernelGGL(kbestprior, dim3(CHUNKS, NB), dim3(256), 0, stream,
                     targets, priors, bestPr);
  hipLaunchKernelGGL(kassign, dim3(CHUNKS, NB), dim3(256), 0, stream,
                     loc, targets, priors, bestPr, conf_t, num_pos, facc, iacc);
  hipLaunchKernelGGL(kce, dim3(2048), dim3(256), 0, stream,
                     conf, conf_t, mine, facc);
  hipLaunchKernelGGL(ktopk, dim3(NB), dim3(1024), 0, stream,
                     mine, num_pos, facc);
  hipLaunchKernelGGL(kfinal, dim3(1), dim3(1), 0, stream, facc, iacc, out);
}